// Round 5
// baseline (1461.266 us; speedup 1.0000x reference)
//
#include <hip/hip_runtime.h>
#include <hip/hip_bf16.h>
#include <cstdint>
#include <cstddef>

typedef __attribute__((ext_vector_type(4))) float f32x4;
typedef __attribute__((ext_vector_type(8))) __bf16 bf16x8;
typedef __attribute__((ext_vector_type(8))) unsigned short ushort8;

__device__ __forceinline__ unsigned short f2b(float f) {
  unsigned int u = __float_as_uint(f);
  u = (u + 0x7fffu + ((u >> 16) & 1u)) >> 16;  // RNE
  return (unsigned short)u;
}
__device__ __forceinline__ float b2f(unsigned short u) {
  return __uint_as_float(((unsigned int)u) << 16);
}

__device__ __forceinline__ f32x4 mfma_bf16(bf16x8 a, bf16x8 b, f32x4 c) {
  return __builtin_amdgcn_mfma_f32_16x16x32_bf16(a, b, c, 0, 0, 0);
}

// ---------------- small utility kernels ----------------

__global__ void cvtw(const float* __restrict__ s, unsigned short* __restrict__ d, int n) {
  int i = blockIdx.x * 256 + threadIdx.x;
  if (i < n) d[i] = f2b(s[i]);
}

// bias_full[h][m][n] = rpb_table[rel_idx[m*64+n]*16 + h], 16*64*64 fp32
__global__ void bias_pre(const float* __restrict__ rpb, const int* __restrict__ rel,
                         float* __restrict__ biasf) {
  int i = blockIdx.x * 256 + threadIdx.x;   // < 65536
  int h = i >> 12, mn = i & 4095;
  biasf[i] = rpb[rel[mn] * 16 + h];
}

// ---------------- window transpose: [B,C,H,W] f32 -> [token][C] bf16 ----------------
// token = win*64 + n ; win = b*256 + (h/8)*16 + (w/8) ; n = (h%8)*8 + (w%8)
__global__ __launch_bounds__(256) void win_tr(const float* __restrict__ src,
                                              unsigned short* __restrict__ dst) {
  __shared__ float T[64 * 65];   // [n][c], pad 65 to spread banks
  int bx = blockIdx.x;
  int win = bx >> 3, cg = bx & 7;
  int b = win >> 8, r1 = (win >> 4) & 15, r2 = win & 15;
  int h0 = r1 * 8, w0c = r2 * 8, c0 = cg * 64;
  int t = threadIdx.x;
#pragma unroll
  for (int pp = 0; pp < 2; ++pp) {
    int p = t + pp * 256;
    int cl = p >> 3, dy = p & 7;
    const float* sp = src + (((size_t)(b * 512 + c0 + cl) * 128 + (h0 + dy)) * 128 + w0c);
    float4 v0 = *(const float4*)sp;
    float4 v1 = *(const float4*)(sp + 4);
    int rb = dy * 8;
    T[(rb + 0) * 65 + cl] = v0.x; T[(rb + 1) * 65 + cl] = v0.y;
    T[(rb + 2) * 65 + cl] = v0.z; T[(rb + 3) * 65 + cl] = v0.w;
    T[(rb + 4) * 65 + cl] = v1.x; T[(rb + 5) * 65 + cl] = v1.y;
    T[(rb + 6) * 65 + cl] = v1.z; T[(rb + 7) * 65 + cl] = v1.w;
  }
  __syncthreads();
  int n = t >> 2, q = t & 3;
  union { unsigned short u[8]; int4 v; } pk0, pk1;
#pragma unroll
  for (int i = 0; i < 8; ++i) pk0.u[i] = f2b(T[n * 65 + q * 16 + i]);
#pragma unroll
  for (int i = 0; i < 8; ++i) pk1.u[i] = f2b(T[n * 65 + q * 16 + 8 + i]);
  size_t o = ((size_t)win * 64 + n) * 512 + c0 + q * 16;
  *(int4*)(dst + o) = pk0.v;
  *(int4*)(dst + o + 8) = pk1.v;
}

// ---------------- inverse transpose: [token][C] bf16 -> [B,C,H,W] f32 ----------------
__global__ __launch_bounds__(256) void inv_tr(const unsigned short* __restrict__ Ot,
                                              float* __restrict__ out) {
  __shared__ float T[64 * 65];   // [c][n]
  int bx = blockIdx.x;
  int win = bx >> 3, cg = bx & 7;
  int b = win >> 8, r1 = (win >> 4) & 15, r2 = win & 15;
  int h0 = r1 * 8, w0c = r2 * 8, c0 = cg * 64;
  int t = threadIdx.x;
  int n = t >> 2, q = t & 3;
  const unsigned short* sp = Ot + ((size_t)win * 64 + n) * 512 + c0 + q * 16;
  union { unsigned short u[8]; int4 v; } r0, r1u;
  r0.v = *(const int4*)sp;
  r1u.v = *(const int4*)(sp + 8);
#pragma unroll
  for (int i = 0; i < 8; ++i) {
    T[(q * 16 + i) * 65 + n] = b2f(r0.u[i]);
    T[(q * 16 + 8 + i) * 65 + n] = b2f(r1u.u[i]);
  }
  __syncthreads();
#pragma unroll
  for (int pp = 0; pp < 2; ++pp) {
    int p = t + pp * 256;
    int cl = p >> 3, dy = p & 7;
    int rb = dy * 8;
    float4 a, bv;
    a.x = T[cl * 65 + rb + 0]; a.y = T[cl * 65 + rb + 1];
    a.z = T[cl * 65 + rb + 2]; a.w = T[cl * 65 + rb + 3];
    bv.x = T[cl * 65 + rb + 4]; bv.y = T[cl * 65 + rb + 5];
    bv.z = T[cl * 65 + rb + 6]; bv.w = T[cl * 65 + rb + 7];
    float* dp = out + (((size_t)(b * 512 + c0 + cl) * 128 + (h0 + dy)) * 128 + w0c);
    *(float4*)dp = a;
    *(float4*)(dp + 4) = bv;
  }
}

// ---------------- NT GEMM: A[M,512] bf16 x W[N,512] bf16 -> epilogue per MODE ----------------
// MODE 0: Q proj  -> out0 = Q [win][head][n][32] bf16, (acc+bias)*scale
// MODE 1: KV proj -> out0 = K, out1 = V, same layout
// MODE 2: O proj  -> out0 = [t][512] bf16 token-major
template <int MODE, int NTL>
__global__ __launch_bounds__(256) void gemm_nt(const unsigned short* __restrict__ A,
                                               const unsigned short* __restrict__ W,
                                               const float* __restrict__ bias,
                                               unsigned short* __restrict__ out0,
                                               unsigned short* __restrict__ out1) {
  __shared__ __align__(16) unsigned short As[2][128 * 40];  // LDT=40 (pad) -> 80B rows (16B-aligned), spread banks
  __shared__ __align__(16) unsigned short Bs[2][128 * 40];
  int bid = blockIdx.x;
  int cpx = gridDim.x >> 3;                      // XCD-chunked swizzle (grid % 8 == 0)
  int wg = (bid & 7) * cpx + (bid >> 3);
  int tn = wg & ((1 << NTL) - 1);
  int tm = wg >> NTL;
  int m0 = tm * 128, n0 = tn * 128;
  int tid = threadIdx.x;
  int w = tid >> 6, lane = tid & 63, g = lane >> 4, c16 = lane & 15;
  int wr = w >> 1, wc = w & 1;
  int srow = tid >> 2, sq = tid & 3;
  const unsigned short* Ap0 = A + (size_t)(m0 + srow) * 512 + sq * 8;
  const unsigned short* Ap1 = Ap0 + 64 * 512;
  const unsigned short* Wp0 = W + (size_t)(n0 + srow) * 512 + sq * 8;
  const unsigned short* Wp1 = Wp0 + 64 * 512;
  int sA0 = srow * 40 + sq * 8;
  int sA1 = (srow + 64) * 40 + sq * 8;
  int aoff = (wr * 64 + c16) * 40 + g * 8;
  int boff = (wc * 64 + c16) * 40 + g * 8;

  int4 ra0 = *(const int4*)Ap0;
  int4 ra1 = *(const int4*)Ap1;
  int4 rb0 = *(const int4*)Wp0;
  int4 rb1 = *(const int4*)Wp1;
  *(int4*)&As[0][sA0] = ra0; *(int4*)&As[0][sA1] = ra1;
  *(int4*)&Bs[0][sA0] = rb0; *(int4*)&Bs[0][sA1] = rb1;
  __syncthreads();

  f32x4 z = {0.f, 0.f, 0.f, 0.f};
  f32x4 acc[4][4];
#pragma unroll
  for (int i = 0; i < 4; ++i)
#pragma unroll
    for (int j = 0; j < 4; ++j) acc[i][j] = z;

  for (int kt = 0; kt < 16; ++kt) {
    int cur = kt & 1;
    bf16x8 af[4], bfv[4];
#pragma unroll
    for (int i = 0; i < 4; ++i) {
      af[i]  = *(const bf16x8*)&As[cur][aoff + i * 640];
      bfv[i] = *(const bf16x8*)&Bs[cur][boff + i * 640];
    }
    if (kt < 15) {
      ra0 = *(const int4*)(Ap0 + (kt + 1) * 32);
      ra1 = *(const int4*)(Ap1 + (kt + 1) * 32);
      rb0 = *(const int4*)(Wp0 + (kt + 1) * 32);
      rb1 = *(const int4*)(Wp1 + (kt + 1) * 32);
    }
#pragma unroll
    for (int fm = 0; fm < 4; ++fm)
#pragma unroll
      for (int fn = 0; fn < 4; ++fn)
        acc[fm][fn] = mfma_bf16(af[fm], bfv[fn], acc[fm][fn]);
    if (kt < 15) {
      int nxt = cur ^ 1;
      *(int4*)&As[nxt][sA0] = ra0; *(int4*)&As[nxt][sA1] = ra1;
      *(int4*)&Bs[nxt][sA0] = rb0; *(int4*)&Bs[nxt][sA1] = rb1;
    }
    __syncthreads();
  }

  int mbase = m0 + wr * 64;
  int nbase = n0 + wc * 64;
#pragma unroll
  for (int fn = 0; fn < 4; ++fn) {
    int o = nbase + fn * 16 + c16;
    float bv = bias[o];
#pragma unroll
    for (int fm = 0; fm < 4; ++fm) {
      f32x4 v = acc[fm][fn];
#pragma unroll
      for (int r = 0; r < 4; ++r) {
        int tt = mbase + fm * 16 + g * 4 + r;
        float val = v[r] + bv;
        if constexpr (MODE == 0) {
          val *= 0.17677669529663688f;  // 32^-0.5
          size_t idx = ((size_t)(tt >> 6) * 16 + (o >> 5)) * 2048 + (size_t)(tt & 63) * 32 + (o & 31);
          out0[idx] = f2b(val);
        } else if constexpr (MODE == 1) {
          int ol = o & 511;
          unsigned short* dst = (o < 512) ? out0 : out1;
          size_t idx = ((size_t)(tt >> 6) * 16 + (ol >> 5)) * 2048 + (size_t)(tt & 63) * 32 + (ol & 31);
          dst[idx] = f2b(val);
        } else {
          out0[(size_t)tt * 512 + o] = f2b(val);
        }
      }
    }
  }
}

// ---------------- per-window attention ----------------
// block = 4 waves; wave w handles heads w*4 .. w*4+3 of its window
#define SWZ(row, byte) ((byte) ^ (((((row) & 7) ^ (((row) >> 3) & 1))) << 4))

__global__ __launch_bounds__(256) void attn_win(const unsigned short* __restrict__ Qb,
                                                const unsigned short* __restrict__ Kb,
                                                const unsigned short* __restrict__ Vb,
                                                const float* __restrict__ biasf,
                                                unsigned short* __restrict__ Oattn) {
  __shared__ __align__(16) unsigned short Pl[4][4096];  // per-wave P [64][64] bf16, swizzled
  __shared__ __align__(16) unsigned short Vt[4][2048];  // per-wave V^T [32][64] bf16, swizzled
  int win = blockIdx.x;
  int tid = threadIdx.x, w = tid >> 6, lane = tid & 63;
  int g = lane >> 4, c16 = lane & 15;
  char* P  = (char*)Pl[w];
  char* VT = (char*)Vt[w];
  f32x4 z = {0.f, 0.f, 0.f, 0.f};
  for (int hh = 0; hh < 4; ++hh) {
    int h = w * 4 + hh;
    const bf16x8* qp = (const bf16x8*)(Qb + ((size_t)win * 16 + h) * 2048);
    const bf16x8* kp = (const bf16x8*)(Kb + ((size_t)win * 16 + h) * 2048);
    bf16x8 qf[4], kf[4];
#pragma unroll
    for (int i = 0; i < 4; ++i) {
      qf[i] = qp[(i * 16 + c16) * 4 + g];
      kf[i] = kp[(i * 16 + c16) * 4 + g];
    }
    f32x4 s[4][4];
#pragma unroll
    for (int i = 0; i < 4; ++i)
#pragma unroll
      for (int j = 0; j < 4; ++j) s[i][j] = z;
#pragma unroll
    for (int fm = 0; fm < 4; ++fm)
#pragma unroll
      for (int fn = 0; fn < 4; ++fn)
        s[fm][fn] = mfma_bf16(qf[fm], kf[fn], s[fm][fn]);

    const float* bh = biasf + h * 4096;
#pragma unroll
    for (int fm = 0; fm < 4; ++fm) {
#pragma unroll
      for (int r = 0; r < 4; ++r) {
        int m = fm * 16 + g * 4 + r;
        float vals[4];
#pragma unroll
        for (int fn = 0; fn < 4; ++fn)
          vals[fn] = s[fm][fn][r] + bh[m * 64 + fn * 16 + c16];
        float mx = fmaxf(fmaxf(vals[0], vals[1]), fmaxf(vals[2], vals[3]));
        mx = fmaxf(mx, __shfl_xor(mx, 1));
        mx = fmaxf(mx, __shfl_xor(mx, 2));
        mx = fmaxf(mx, __shfl_xor(mx, 4));
        mx = fmaxf(mx, __shfl_xor(mx, 8));
        float sum = 0.f;
#pragma unroll
        for (int fn = 0; fn < 4; ++fn) { vals[fn] = __expf(vals[fn] - mx); sum += vals[fn]; }
        sum += __shfl_xor(sum, 1);
        sum += __shfl_xor(sum, 2);
        sum += __shfl_xor(sum, 4);
        sum += __shfl_xor(sum, 8);
        float inv = 1.0f / sum;
#pragma unroll
        for (int fn = 0; fn < 4; ++fn) {
          int col = fn * 16 + c16;
          int byte = SWZ(m, m * 128 + col * 2);
          *(unsigned short*)(P + byte) = f2b(vals[fn] * inv);
        }
      }
    }
    // V load + LDS transpose ([n][c] -> [c][n])
    const ushort8* vp = (const ushort8*)(Vb + ((size_t)win * 16 + h) * 2048);
#pragma unroll
    for (int i = 0; i < 4; ++i) {
      ushort8 vv = vp[(i * 16 + c16) * 4 + g];
#pragma unroll
      for (int j = 0; j < 8; ++j) {
        int row = g * 8 + j;       // channel
        int col = i * 16 + c16;    // token
        int byte = SWZ(row, row * 128 + col * 2);
        *(unsigned short*)(VT + byte) = vv[j];
      }
    }
    // PV
    f32x4 oa[4][2];
#pragma unroll
    for (int i = 0; i < 4; ++i) { oa[i][0] = z; oa[i][1] = z; }
#pragma unroll
    for (int ks = 0; ks < 2; ++ks) {
      bf16x8 pa[4], vbf[2];
#pragma unroll
      for (int fm = 0; fm < 4; ++fm) {
        int row = fm * 16 + c16;
        pa[fm] = *(const bf16x8*)(P + SWZ(row, row * 128 + ks * 64 + g * 16));
      }
#pragma unroll
      for (int fc = 0; fc < 2; ++fc) {
        int row = fc * 16 + c16;
        vbf[fc] = *(const bf16x8*)(VT + SWZ(row, row * 128 + ks * 64 + g * 16));
      }
#pragma unroll
      for (int fm = 0; fm < 4; ++fm)
#pragma unroll
        for (int fc = 0; fc < 2; ++fc)
          oa[fm][fc] = mfma_bf16(pa[fm], vbf[fc], oa[fm][fc]);
    }
#pragma unroll
    for (int fm = 0; fm < 4; ++fm)
#pragma unroll
      for (int fc = 0; fc < 2; ++fc)
#pragma unroll
        for (int r = 0; r < 4; ++r) {
          int m = fm * 16 + g * 4 + r;
          Oattn[((size_t)win * 64 + m) * 512 + h * 32 + fc * 16 + c16] = f2b(oa[fm][fc][r]);
        }
  }
}

// ---------------- launch ----------------
extern "C" void kernel_launch(void* const* d_in, const int* in_sizes, int n_in,
                              void* d_out, int out_size, void* d_ws, size_t ws_size,
                              hipStream_t stream) {
  const float* xa  = (const float*)d_in[0];
  const float* xb  = (const float*)d_in[1];
  const float* Wq  = (const float*)d_in[2];
  const float* bq  = (const float*)d_in[3];
  const float* Wkv = (const float*)d_in[4];
  const float* bkv = (const float*)d_in[5];
  const float* Wo  = (const float*)d_in[6];
  const float* bo  = (const float*)d_in[7];
  const float* rpb = (const float*)d_in[8];
  const int*   rel = (const int*)d_in[9];
  float* out = (float*)d_out;

  // Workspace layout (requires only ~258.3 MiB):
  //   ws[0,128MiB)      R0: At / Bt / Oattn (bf16, reused sequentially)
  //   ws[128,256MiB)    Qb (bf16)  -- later reused as Ot (bf16 token-major)
  //   ws[256MiB,+2.3MB) biasf (256KB), WqB (512KB), WkvB (1MB), WoB (512KB)
  // K and V (128 MiB bf16 each) live in d_out (256 MiB fp32) as scratch;
  // they are dead before inv_tr overwrites every byte of d_out.
  char* ws = (char*)d_ws;
  unsigned short* R0 = (unsigned short*)ws;
  unsigned short* Qb = (unsigned short*)(ws + (size_t)134217728);
  unsigned short* Ot = Qb;  // reuse after Qb is dead
  unsigned short* Kb = (unsigned short*)d_out;
  unsigned short* Vb = Kb + (size_t)67108864;
  char* extra        = ws + (size_t)268435456;
  float* biasf          = (float*)extra;
  unsigned short* WqB   = (unsigned short*)(extra + 262144);
  unsigned short* WkvB  = (unsigned short*)(extra + 262144 + 524288);
  unsigned short* WoB   = (unsigned short*)(extra + 262144 + 524288 + 1048576);

  cvtw<<<1024, 256, 0, stream>>>(Wq,  WqB,  262144);
  cvtw<<<2048, 256, 0, stream>>>(Wkv, WkvB, 524288);
  cvtw<<<1024, 256, 0, stream>>>(Wo,  WoB,  262144);
  bias_pre<<<256, 256, 0, stream>>>(rpb, rel, biasf);

  win_tr<<<16384, 256, 0, stream>>>(xa, R0);
  gemm_nt<0, 2><<<4096, 256, 0, stream>>>(R0, WqB, bq, Qb, nullptr);
  win_tr<<<16384, 256, 0, stream>>>(xb, R0);
  gemm_nt<1, 3><<<8192, 256, 0, stream>>>(R0, WkvB, bkv, Kb, Vb);
  attn_win<<<2048, 256, 0, stream>>>(Qb, Kb, Vb, biasf, R0);
  gemm_nt<2, 2><<<4096, 256, 0, stream>>>(R0, WoB, bo, Ot, nullptr);
  inv_tr<<<16384, 256, 0, stream>>>(Ot, out);
}

// Round 6
// 1390.299 us; speedup vs baseline: 1.0510x; 1.0510x over previous
//
#include <hip/hip_runtime.h>
#include <hip/hip_bf16.h>
#include <cstdint>
#include <cstddef>

typedef __attribute__((ext_vector_type(4))) float f32x4;
typedef __attribute__((ext_vector_type(8))) __bf16 bf16x8;
typedef __attribute__((ext_vector_type(8))) unsigned short ushort8;

typedef __attribute__((address_space(3))) unsigned int lds_u32;
typedef const __attribute__((address_space(1))) unsigned int glb_u32;

__device__ __forceinline__ unsigned short f2b(float f) {
  unsigned int u = __float_as_uint(f);
  u = (u + 0x7fffu + ((u >> 16) & 1u)) >> 16;  // RNE
  return (unsigned short)u;
}
__device__ __forceinline__ float b2f(unsigned short u) {
  return __uint_as_float(((unsigned int)u) << 16);
}

__device__ __forceinline__ f32x4 mfma_bf16(bf16x8 a, bf16x8 b, f32x4 c) {
  return __builtin_amdgcn_mfma_f32_16x16x32_bf16(a, b, c, 0, 0, 0);
}

// async global->LDS, 16B per lane; l must be wave-uniform base (lane*16 added by HW)
__device__ __forceinline__ void gload16(const unsigned short* g, void* l) {
  __builtin_amdgcn_global_load_lds((glb_u32*)g, (lds_u32*)l, 16, 0, 0);
}

// ---------------- small utility kernels ----------------

__global__ void cvtw(const float* __restrict__ s, unsigned short* __restrict__ d, int n) {
  int i = blockIdx.x * 256 + threadIdx.x;
  if (i < n) d[i] = f2b(s[i]);
}

// bias_full[h][m][n] = rpb_table[rel_idx[m*64+n]*16 + h], 16*64*64 fp32
__global__ void bias_pre(const float* __restrict__ rpb, const int* __restrict__ rel,
                         float* __restrict__ biasf) {
  int i = blockIdx.x * 256 + threadIdx.x;   // < 65536
  int h = i >> 12, mn = i & 4095;
  biasf[i] = rpb[rel[mn] * 16 + h];
}

// ---------------- window transpose: [B,C,H,W] f32 -> [token][C] bf16 ----------------
__global__ __launch_bounds__(256) void win_tr(const float* __restrict__ src,
                                              unsigned short* __restrict__ dst) {
  __shared__ float T[64 * 65];
  int bx = blockIdx.x;
  int win = bx >> 3, cg = bx & 7;
  int b = win >> 8, r1 = (win >> 4) & 15, r2 = win & 15;
  int h0 = r1 * 8, w0c = r2 * 8, c0 = cg * 64;
  int t = threadIdx.x;
#pragma unroll
  for (int pp = 0; pp < 2; ++pp) {
    int p = t + pp * 256;
    int cl = p >> 3, dy = p & 7;
    const float* sp = src + (((size_t)(b * 512 + c0 + cl) * 128 + (h0 + dy)) * 128 + w0c);
    float4 v0 = *(const float4*)sp;
    float4 v1 = *(const float4*)(sp + 4);
    int rb = dy * 8;
    T[(rb + 0) * 65 + cl] = v0.x; T[(rb + 1) * 65 + cl] = v0.y;
    T[(rb + 2) * 65 + cl] = v0.z; T[(rb + 3) * 65 + cl] = v0.w;
    T[(rb + 4) * 65 + cl] = v1.x; T[(rb + 5) * 65 + cl] = v1.y;
    T[(rb + 6) * 65 + cl] = v1.z; T[(rb + 7) * 65 + cl] = v1.w;
  }
  __syncthreads();
  int n = t >> 2, q = t & 3;
  union { unsigned short u[8]; int4 v; } pk0, pk1;
#pragma unroll
  for (int i = 0; i < 8; ++i) pk0.u[i] = f2b(T[n * 65 + q * 16 + i]);
#pragma unroll
  for (int i = 0; i < 8; ++i) pk1.u[i] = f2b(T[n * 65 + q * 16 + 8 + i]);
  size_t o = ((size_t)win * 64 + n) * 512 + c0 + q * 16;
  *(int4*)(dst + o) = pk0.v;
  *(int4*)(dst + o + 8) = pk1.v;
}

// ---------------- inverse transpose: [token][C] bf16 -> [B,C,H,W] f32 ----------------
__global__ __launch_bounds__(256) void inv_tr(const unsigned short* __restrict__ Ot,
                                              float* __restrict__ out) {
  __shared__ float T[64 * 65];
  int bx = blockIdx.x;
  int win = bx >> 3, cg = bx & 7;
  int b = win >> 8, r1 = (win >> 4) & 15, r2 = win & 15;
  int h0 = r1 * 8, w0c = r2 * 8, c0 = cg * 64;
  int t = threadIdx.x;
  int n = t >> 2, q = t & 3;
  const unsigned short* sp = Ot + ((size_t)win * 64 + n) * 512 + c0 + q * 16;
  union { unsigned short u[8]; int4 v; } r0, r1u;
  r0.v = *(const int4*)sp;
  r1u.v = *(const int4*)(sp + 8);
#pragma unroll
  for (int i = 0; i < 8; ++i) {
    T[(q * 16 + i) * 65 + n] = b2f(r0.u[i]);
    T[(q * 16 + 8 + i) * 65 + n] = b2f(r1u.u[i]);
  }
  __syncthreads();
#pragma unroll
  for (int pp = 0; pp < 2; ++pp) {
    int p = t + pp * 256;
    int cl = p >> 3, dy = p & 7;
    int rb = dy * 8;
    float4 a, bv;
    a.x = T[cl * 65 + rb + 0]; a.y = T[cl * 65 + rb + 1];
    a.z = T[cl * 65 + rb + 2]; a.w = T[cl * 65 + rb + 3];
    bv.x = T[cl * 65 + rb + 4]; bv.y = T[cl * 65 + rb + 5];
    bv.z = T[cl * 65 + rb + 6]; bv.w = T[cl * 65 + rb + 7];
    float* dp = out + (((size_t)(b * 512 + c0 + cl) * 128 + (h0 + dy)) * 128 + w0c);
    *(float4*)dp = a;
    *(float4*)(dp + 4) = bv;
  }
}

// ---------------- NT GEMM (m97 structure): A[M,512] x W[N,512], global_load_lds staging ----
// MODE 0: Q proj  -> out0 = Q [win][head][n][32] bf16, (acc+bias)*scale
// MODE 1: KV proj -> out0 = K, out1 = V, same layout
// MODE 2: O proj  -> out0 = [t][512] bf16 token-major
template <int MODE, int NTL>
__global__ __launch_bounds__(256) void gemm_nt(const unsigned short* __restrict__ A,
                                               const unsigned short* __restrict__ W,
                                               const float* __restrict__ bias,
                                               unsigned short* __restrict__ out0,
                                               unsigned short* __restrict__ out1) {
  __shared__ __align__(16) unsigned short As[2][128 * 32];  // linear [row][32] (64B rows)
  __shared__ __align__(16) unsigned short Bs[2][128 * 32];
  int bid = blockIdx.x;
  int cpx = gridDim.x >> 3;                      // XCD-chunked swizzle (grid % 8 == 0)
  int wg = (bid & 7) * cpx + (bid >> 3);
  int tn = wg & ((1 << NTL) - 1);
  int tm = wg >> NTL;
  int m0 = tm * 128, n0 = tn * 128;
  int tid = threadIdx.x;
  int w = tid >> 6, lane = tid & 63, g = lane >> 4, c16 = lane & 15;
  int wr = w >> 1, wc = w & 1;

  // staging map: flat idx = p*256 + tid ; row = idx>>2, col = (idx&3)*8; lds byte = idx*16
  int r0 = tid >> 2, cc0 = (tid & 3) * 8;
  int r1 = (256 + tid) >> 2, cc1 = (tid & 3) * 8;
  const unsigned short* Ag0 = A + (size_t)(m0 + r0) * 512 + cc0;
  const unsigned short* Ag1 = A + (size_t)(m0 + r1) * 512 + cc1;
  const unsigned short* Wg0 = W + (size_t)(n0 + r0) * 512 + cc0;
  const unsigned short* Wg1 = W + (size_t)(n0 + r1) * 512 + cc1;

#define STAGE(b, kk) { \
    char* la = (char*)As[b] + w * 1024; \
    char* lb = (char*)Bs[b] + w * 1024; \
    gload16(Ag0 + (kk) * 32, la); \
    gload16(Ag1 + (kk) * 32, la + 4096); \
    gload16(Wg0 + (kk) * 32, lb); \
    gload16(Wg1 + (kk) * 32, lb + 4096); }

  STAGE(0, 0);
  __syncthreads();

  f32x4 z = {0.f, 0.f, 0.f, 0.f};
  f32x4 acc[4][4];
#pragma unroll
  for (int i = 0; i < 4; ++i)
#pragma unroll
    for (int j = 0; j < 4; ++j) acc[i][j] = z;

  int aoff = (wr * 64 + c16) * 64 + g * 16;   // bytes
  int boff = (wc * 64 + c16) * 64 + g * 16;

  for (int kt = 0; kt < 16; ++kt) {
    int cur = kt & 1;
    if (kt < 15) STAGE(cur ^ 1, kt + 1);
    bf16x8 af[4], bfv[4];
#pragma unroll
    for (int i = 0; i < 4; ++i) {
      af[i]  = *(const bf16x8*)((char*)As[cur] + aoff + i * 1024);
      bfv[i] = *(const bf16x8*)((char*)Bs[cur] + boff + i * 1024);
    }
#pragma unroll
    for (int fm = 0; fm < 4; ++fm)
#pragma unroll
      for (int fn = 0; fn < 4; ++fn)
        acc[fm][fn] = mfma_bf16(af[fm], bfv[fn], acc[fm][fn]);
    __syncthreads();
  }
#undef STAGE

  int mbase = m0 + wr * 64;
  int nbase = n0 + wc * 64;
#pragma unroll
  for (int fn = 0; fn < 4; ++fn) {
    int o = nbase + fn * 16 + c16;
    float bv = bias[o];
#pragma unroll
    for (int fm = 0; fm < 4; ++fm) {
      f32x4 v = acc[fm][fn];
#pragma unroll
      for (int r = 0; r < 4; ++r) {
        int tt = mbase + fm * 16 + g * 4 + r;
        float val = v[r] + bv;
        if constexpr (MODE == 0) {
          val *= 0.17677669529663688f;  // 32^-0.5
          size_t idx = ((size_t)(tt >> 6) * 16 + (o >> 5)) * 2048 + (size_t)(tt & 63) * 32 + (o & 31);
          out0[idx] = f2b(val);
        } else if constexpr (MODE == 1) {
          int ol = o & 511;
          unsigned short* dst = (o < 512) ? out0 : out1;
          size_t idx = ((size_t)(tt >> 6) * 16 + (ol >> 5)) * 2048 + (size_t)(tt & 63) * 32 + (ol & 31);
          dst[idx] = f2b(val);
        } else {
          out0[(size_t)tt * 512 + o] = f2b(val);
        }
      }
    }
  }
}

// ---------------- per-window attention ----------------
// block = 4 waves; wave w handles heads w*4 .. w*4+3 of its window.
// LDS per wave: P16 [16][64] (2 KB, one fm-tile at a time) + V^T [32][64] (4 KB) = 6 KB.
#define SWZ(row, byte) ((byte) ^ (((((row) & 7) ^ (((row) >> 3) & 1))) << 4))

__global__ __launch_bounds__(256) void attn_win(const unsigned short* __restrict__ Qb,
                                                const unsigned short* __restrict__ Kb,
                                                const unsigned short* __restrict__ Vb,
                                                const float* __restrict__ biasf,
                                                unsigned short* __restrict__ Oattn) {
  __shared__ __align__(16) unsigned short Pl[4][1024];  // per-wave P16 [16][64] bf16, swizzled
  __shared__ __align__(16) unsigned short Vt[4][2048];  // per-wave V^T [32][64] bf16, swizzled
  int win = blockIdx.x;
  int tid = threadIdx.x, w = tid >> 6, lane = tid & 63;
  int g = lane >> 4, c16 = lane & 15;
  char* P  = (char*)Pl[w];
  char* VT = (char*)Vt[w];
  f32x4 z = {0.f, 0.f, 0.f, 0.f};
  for (int hh = 0; hh < 4; ++hh) {
    int h = w * 4 + hh;
    const bf16x8* qp = (const bf16x8*)(Qb + ((size_t)win * 16 + h) * 2048);
    const bf16x8* kp = (const bf16x8*)(Kb + ((size_t)win * 16 + h) * 2048);
    bf16x8 qf[4], kf[4];
#pragma unroll
    for (int i = 0; i < 4; ++i) {
      qf[i] = qp[(i * 16 + c16) * 4 + g];
      kf[i] = kp[(i * 16 + c16) * 4 + g];
    }
    f32x4 s[4][4];
#pragma unroll
    for (int i = 0; i < 4; ++i)
#pragma unroll
      for (int j = 0; j < 4; ++j) s[i][j] = z;
#pragma unroll
    for (int fm = 0; fm < 4; ++fm)
#pragma unroll
      for (int fn = 0; fn < 4; ++fn)
        s[fm][fn] = mfma_bf16(qf[fm], kf[fn], s[fm][fn]);

    // V load + LDS transpose ([n][c] -> [c][n])
    const ushort8* vp = (const ushort8*)(Vb + ((size_t)win * 16 + h) * 2048);
#pragma unroll
    for (int i = 0; i < 4; ++i) {
      ushort8 vv = vp[(i * 16 + c16) * 4 + g];
#pragma unroll
      for (int j = 0; j < 8; ++j) {
        int row = g * 8 + j;       // channel
        int col = i * 16 + c16;    // token
        int byte = SWZ(row, row * 128 + col * 2);
        *(unsigned short*)(VT + byte) = vv[j];
      }
    }
    // V B-fragments (channel = fc*16+c16, token = ks*32 + g*8 + j)
    bf16x8 vbf[2][2];
#pragma unroll
    for (int ks = 0; ks < 2; ++ks)
#pragma unroll
      for (int fc = 0; fc < 2; ++fc) {
        int row = fc * 16 + c16;
        vbf[ks][fc] = *(const bf16x8*)(VT + SWZ(row, row * 128 + ks * 64 + g * 16));
      }

    const float* bh = biasf + h * 4096;
#pragma unroll
    for (int fm = 0; fm < 4; ++fm) {
      // softmax rows of this 16-row tile -> P16
#pragma unroll
      for (int r = 0; r < 4; ++r) {
        int m = fm * 16 + g * 4 + r;
        int lm = g * 4 + r;
        float vals[4];
#pragma unroll
        for (int fn = 0; fn < 4; ++fn)
          vals[fn] = s[fm][fn][r] + bh[m * 64 + fn * 16 + c16];
        float mx = fmaxf(fmaxf(vals[0], vals[1]), fmaxf(vals[2], vals[3]));
        mx = fmaxf(mx, __shfl_xor(mx, 1));
        mx = fmaxf(mx, __shfl_xor(mx, 2));
        mx = fmaxf(mx, __shfl_xor(mx, 4));
        mx = fmaxf(mx, __shfl_xor(mx, 8));
        float sum = 0.f;
#pragma unroll
        for (int fn = 0; fn < 4; ++fn) { vals[fn] = __expf(vals[fn] - mx); sum += vals[fn]; }
        sum += __shfl_xor(sum, 1);
        sum += __shfl_xor(sum, 2);
        sum += __shfl_xor(sum, 4);
        sum += __shfl_xor(sum, 8);
        float inv = 1.0f / sum;
#pragma unroll
        for (int fn = 0; fn < 4; ++fn) {
          int col = fn * 16 + c16;
          int byte = SWZ(lm, lm * 128 + col * 2);
          *(unsigned short*)(P + byte) = f2b(vals[fn] * inv);
        }
      }
      // PV for this fm-tile (in-order wave-private LDS: writes above complete before reads)
      bf16x8 pa0 = *(const bf16x8*)(P + SWZ(c16, c16 * 128 + g * 16));
      bf16x8 pa1 = *(const bf16x8*)(P + SWZ(c16, c16 * 128 + 64 + g * 16));
      f32x4 o0 = z, o1 = z;
      o0 = mfma_bf16(pa0, vbf[0][0], o0);
      o0 = mfma_bf16(pa1, vbf[1][0], o0);
      o1 = mfma_bf16(pa0, vbf[0][1], o1);
      o1 = mfma_bf16(pa1, vbf[1][1], o1);
#pragma unroll
      for (int r = 0; r < 4; ++r) {
        int m = fm * 16 + g * 4 + r;
        size_t ob = ((size_t)win * 64 + m) * 512 + h * 32;
        Oattn[ob + c16] = f2b(o0[r]);
        Oattn[ob + 16 + c16] = f2b(o1[r]);
      }
    }
  }
}

// ---------------- launch ----------------
extern "C" void kernel_launch(void* const* d_in, const int* in_sizes, int n_in,
                              void* d_out, int out_size, void* d_ws, size_t ws_size,
                              hipStream_t stream) {
  const float* xa  = (const float*)d_in[0];
  const float* xb  = (const float*)d_in[1];
  const float* Wq  = (const float*)d_in[2];
  const float* bq  = (const float*)d_in[3];
  const float* Wkv = (const float*)d_in[4];
  const float* bkv = (const float*)d_in[5];
  const float* Wo  = (const float*)d_in[6];
  const float* bo  = (const float*)d_in[7];
  const float* rpb = (const float*)d_in[8];
  const int*   rel = (const int*)d_in[9];
  float* out = (float*)d_out;

  // Workspace layout (~258.3 MiB):
  //   ws[0,128MiB)      R0: At / Bt / Oattn (bf16, reused sequentially)
  //   ws[128,256MiB)    Qb (bf16)  -- later reused as Ot (bf16 token-major)
  //   ws[256MiB,+2.3MB) biasf (256KB), WqB (512KB), WkvB (1MB), WoB (512KB)
  // K and V (128 MiB bf16 each) live in d_out (256 MiB fp32) as scratch;
  // they are dead before inv_tr overwrites every byte of d_out.
  char* ws = (char*)d_ws;
  unsigned short* R0 = (unsigned short*)ws;
  unsigned short* Qb = (unsigned short*)(ws + (size_t)134217728);
  unsigned short* Ot = Qb;  // reuse after Qb is dead
  unsigned short* Kb = (unsigned short*)d_out;
  unsigned short* Vb = Kb + (size_t)67108864;
  char* extra        = ws + (size_t)268435456;
  float* biasf          = (float*)extra;
  unsigned short* WqB   = (unsigned short*)(extra + 262144);
  unsigned short* WkvB  = (unsigned short*)(extra + 262144 + 524288);
  unsigned short* WoB   = (unsigned short*)(extra + 262144 + 524288 + 1048576);

  cvtw<<<1024, 256, 0, stream>>>(Wq,  WqB,  262144);
  cvtw<<<2048, 256, 0, stream>>>(Wkv, WkvB, 524288);
  cvtw<<<1024, 256, 0, stream>>>(Wo,  WoB,  262144);
  bias_pre<<<256, 256, 0, stream>>>(rpb, rel, biasf);

  win_tr<<<16384, 256, 0, stream>>>(xa, R0);
  gemm_nt<0, 2><<<4096, 256, 0, stream>>>(R0, WqB, bq, Qb, nullptr);
  win_tr<<<16384, 256, 0, stream>>>(xb, R0);
  gemm_nt<1, 3><<<8192, 256, 0, stream>>>(R0, WkvB, bkv, Kb, Vb);
  attn_win<<<2048, 256, 0, stream>>>(Qb, Kb, Vb, biasf, R0);
  gemm_nt<2, 2><<<4096, 256, 0, stream>>>(R0, WoB, bo, Ot, nullptr);
  inv_tr<<<16384, 256, 0, stream>>>(Ot, out);
}